// Round 1
// baseline (1779.209 us; speedup 1.0000x reference)
//
#include <hip/hip_runtime.h>
#include <hip/hip_bf16.h>

#define FDIM 512
#define HDIM 256
#define CDIM 64
#define KSTEPS 10

typedef __attribute__((ext_vector_type(8))) short bf16x8;
typedef __attribute__((ext_vector_type(4))) float f32x4;

static __device__ __forceinline__ unsigned short f2bf(float f) {
  union { float f; unsigned int u; } x; x.f = f;
  unsigned int u = x.u;
  return (unsigned short)((u + 0x7fffu + ((u >> 16) & 1u)) >> 16);  // RNE
}

// ---------------- weight prep: fp32 [K][N] -> bf16 transposed [N][K] -------
__global__ void prep_w(const float* __restrict__ W1, const float* __restrict__ W2,
                       unsigned short* __restrict__ W1t, unsigned short* __restrict__ W2t) {
  int i = blockIdx.x * 256 + threadIdx.x;
  if (i < FDIM * HDIM) { int k = i / HDIM, n = i % HDIM; W1t[(size_t)n * FDIM + k] = f2bf(W1[i]); }
  if (i < HDIM * CDIM) { int k = i / CDIM, n = i % CDIM; W2t[(size_t)n * HDIM + k] = f2bf(W2[i]); }
}

// ---------------- graph prep -----------------------------------------------
__global__ void deg_k(const int* __restrict__ dst, int* __restrict__ deg, int E) {
  int i = blockIdx.x * 256 + threadIdx.x;
  if (i < E) atomicAdd(&deg[dst[i]], 1);
}

__global__ void dinv_k(const int* __restrict__ deg, float* __restrict__ dinv, int n) {
  int i = blockIdx.x * 256 + threadIdx.x;
  if (i < n) dinv[i] = rsqrtf((float)deg[i] + 1.0f);  // +1 self-loop
}

__global__ void scan_block(const int* __restrict__ deg, int* __restrict__ out,
                           int* __restrict__ bsum, int n) {
  __shared__ int tmp[1024];
  int i = blockIdx.x * 1024 + threadIdx.x;
  int v = (i < n) ? deg[i] : 0;
  tmp[threadIdx.x] = v;
  __syncthreads();
  for (int off = 1; off < 1024; off <<= 1) {
    int t = (threadIdx.x >= off) ? tmp[threadIdx.x - off] : 0;
    __syncthreads();
    tmp[threadIdx.x] += t;
    __syncthreads();
  }
  if (i < n) out[i] = tmp[threadIdx.x] - v;  // exclusive
  if (threadIdx.x == 1023) bsum[blockIdx.x] = tmp[1023];
}

__global__ void scan_sums(const int* __restrict__ bsum, int* __restrict__ boff, int nb) {
  if (threadIdx.x == 0 && blockIdx.x == 0) {
    int run = 0;
    for (int b = 0; b < nb; ++b) { boff[b] = run; run += bsum[b]; }
  }
}

__global__ void scan_add(int* __restrict__ rowptr, int* __restrict__ cursor,
                         const int* __restrict__ boff, int n, int total) {
  int i = blockIdx.x * 1024 + threadIdx.x;
  if (i < n) {
    int v = rowptr[i] + boff[blockIdx.x];
    rowptr[i] = v;
    cursor[i] = v;
  }
  if (i == 0) rowptr[n] = total;
}

__global__ void fill_k(const int* __restrict__ src, const int* __restrict__ dst,
                       const float* __restrict__ dinv, int* __restrict__ cursor,
                       int* __restrict__ col, float* __restrict__ wsrc, int E) {
  int i = blockIdx.x * 256 + threadIdx.x;
  if (i < E) {
    int s = src[i], d = dst[i];
    int p = atomicAdd(&cursor[d], 1);
    col[p] = s;
    wsrc[p] = dinv[s];
  }
}

// ---------------- bf16 MFMA GEMM: C[M,N] = act(A[M,K] @ Bt[N,K]^T + bias) ---
// block = 256 threads (4 waves), tile 64(M) x 64(N), BK=32.
// wave w computes rows [16w,16w+16) x all 64 cols via 4 mfma_f32_16x16x32_bf16.
template <int A_F32, int OUT_RELU_BF16>
__global__ __launch_bounds__(256) void gemm_k(const void* __restrict__ Ap,
                                              const unsigned short* __restrict__ Bt,
                                              const float* __restrict__ bias,
                                              void* __restrict__ Cp, int M, int N, int K) {
  __shared__ unsigned short Al[64][40];  // +8 pad: 80B row stride
  __shared__ unsigned short Bl[64][40];
  const int tid = threadIdx.x;
  const int wid = tid >> 6;
  const int lane = tid & 63;
  const int m0 = blockIdx.x * 64;
  const int n0 = blockIdx.y * 64;
  const int srow = tid >> 2;        // 0..63
  const int scg = (tid & 3) * 8;    // 0,8,16,24
  f32x4 acc[4] = {{0.f, 0.f, 0.f, 0.f}, {0.f, 0.f, 0.f, 0.f},
                  {0.f, 0.f, 0.f, 0.f}, {0.f, 0.f, 0.f, 0.f}};
  for (int k0 = 0; k0 < K; k0 += 32) {
    // stage A tile 64x32 (convert fp32->bf16 if needed)
    {
      const int gr = m0 + srow;
      unsigned short av[8];
      if (A_F32) {
        const float* A = (const float*)Ap;
        if (gr < M) {
          const float* p = A + (size_t)gr * K + k0 + scg;
#pragma unroll
          for (int j = 0; j < 8; ++j) av[j] = f2bf(p[j]);
        } else {
#pragma unroll
          for (int j = 0; j < 8; ++j) av[j] = 0;
        }
      } else {
        const unsigned short* A = (const unsigned short*)Ap;
        if (gr < M) {
          bf16x8 v = *(const bf16x8*)(A + (size_t)gr * K + k0 + scg);
          *(bf16x8*)av = v;
        } else {
#pragma unroll
          for (int j = 0; j < 8; ++j) av[j] = 0;
        }
      }
      *(bf16x8*)(&Al[srow][scg]) = *(bf16x8*)av;
    }
    // stage B tile (Bt is [N][K] so rows are contiguous in K)
    {
      bf16x8 v = *(const bf16x8*)(Bt + (size_t)(n0 + srow) * K + k0 + scg);
      *(bf16x8*)(&Bl[srow][scg]) = v;
    }
    __syncthreads();
    bf16x8 a = *(const bf16x8*)(&Al[wid * 16 + (lane & 15)][(lane >> 4) * 8]);
#pragma unroll
    for (int nf = 0; nf < 4; ++nf) {
      bf16x8 b = *(const bf16x8*)(&Bl[nf * 16 + (lane & 15)][(lane >> 4) * 8]);
      acc[nf] = __builtin_amdgcn_mfma_f32_16x16x32_bf16(a, b, acc[nf], 0, 0, 0);
    }
    __syncthreads();
  }
  // epilogue: C/D layout col=lane&15, row=(lane>>4)*4+r
#pragma unroll
  for (int nf = 0; nf < 4; ++nf) {
    const int colg = n0 + nf * 16 + (lane & 15);
    const float bb = bias[colg];
#pragma unroll
    for (int r = 0; r < 4; ++r) {
      const int rowg = m0 + wid * 16 + (lane >> 4) * 4 + r;
      if (rowg < M) {
        float v = acc[nf][r] + bb;
        if (OUT_RELU_BF16) {
          v = fmaxf(v, 0.0f);
          ((unsigned short*)Cp)[(size_t)rowg * N + colg] = f2bf(v);
        } else {
          ((float*)Cp)[(size_t)rowg * N + colg] = v;
        }
      }
    }
  }
}

// ---------------- APPNP propagation step -----------------------------------
// one wave per dst row; 64 lanes = 64 channels; CSR gather-reduce.
// agg[r] = dinv[r]*(sum_e wsrc[e]*h[col[e]]) + dinv[r]^2*h[r]
// h_out = 0.9*agg + 0.1*h0
__global__ __launch_bounds__(256) void spmv_k(const int* __restrict__ rowptr,
                                              const int* __restrict__ col,
                                              const float* __restrict__ wsrc,
                                              const float* __restrict__ dinv,
                                              const float* __restrict__ hin,
                                              const float* __restrict__ h0,
                                              float* __restrict__ hout, int n) {
  const int r = blockIdx.x * 4 + (threadIdx.x >> 6);
  if (r >= n) return;
  const int lane = threadIdx.x & 63;
  const int e0 = rowptr[r], e1 = rowptr[r + 1];
  float acc = 0.0f;
  int e = e0;
  for (; e + 3 < e1; e += 4) {
    const int s0 = col[e], s1 = col[e + 1], s2 = col[e + 2], s3 = col[e + 3];
    const float w0 = wsrc[e], w1 = wsrc[e + 1], w2 = wsrc[e + 2], w3 = wsrc[e + 3];
    const float v0 = hin[(size_t)s0 * 64 + lane];
    const float v1 = hin[(size_t)s1 * 64 + lane];
    const float v2 = hin[(size_t)s2 * 64 + lane];
    const float v3 = hin[(size_t)s3 * 64 + lane];
    acc += w0 * v0 + w1 * v1 + w2 * v2 + w3 * v3;
  }
  for (; e < e1; ++e) acc += wsrc[e] * hin[(size_t)col[e] * 64 + lane];
  const float di = dinv[r];
  const float agg = di * acc + di * di * hin[(size_t)r * 64 + lane];
  hout[(size_t)r * 64 + lane] = 0.9f * agg + 0.1f * h0[(size_t)r * 64 + lane];
}

// ---------------- log_softmax over 64 classes ------------------------------
__global__ __launch_bounds__(256) void logsoftmax_k(const float* __restrict__ h,
                                                    float* __restrict__ out, int n) {
  const int r = blockIdx.x * 4 + (threadIdx.x >> 6);
  if (r >= n) return;
  const int lane = threadIdx.x & 63;
  float v = h[(size_t)r * 64 + lane];
  float m = v;
#pragma unroll
  for (int o = 32; o; o >>= 1) m = fmaxf(m, __shfl_xor(m, o, 64));
  float ex = expf(v - m);
  float s = ex;
#pragma unroll
  for (int o = 32; o; o >>= 1) s += __shfl_xor(s, o, 64);
  out[(size_t)r * 64 + lane] = v - m - logf(s);
}

extern "C" void kernel_launch(void* const* d_in, const int* in_sizes, int n_in,
                              void* d_out, int out_size, void* d_ws, size_t ws_size,
                              hipStream_t stream) {
  const float* x = (const float*)d_in[0];
  const float* W1 = (const float*)d_in[1];
  const float* b1 = (const float*)d_in[2];
  const float* W2 = (const float*)d_in[3];
  const float* b2 = (const float*)d_in[4];
  const int* ei = (const int*)d_in[5];
  const int E = in_sizes[5] / 2;
  const int N = in_sizes[0] / FDIM;
  const int* src = ei;
  const int* dst = ei + E;

  char* wp = (char*)d_ws;
  auto alloc = [&](size_t b) {
    char* p = wp;
    wp += (b + 255) & ~(size_t)255;
    return p;
  };
  unsigned short* W1t = (unsigned short*)alloc((size_t)HDIM * FDIM * 2);
  unsigned short* W2t = (unsigned short*)alloc((size_t)CDIM * HDIM * 2);
  unsigned short* h1 = (unsigned short*)alloc((size_t)N * HDIM * 2);
  float* h0 = (float*)alloc((size_t)N * CDIM * 4);
  float* hA = (float*)alloc((size_t)N * CDIM * 4);
  float* hB = (float*)alloc((size_t)N * CDIM * 4);
  int* deg = (int*)alloc((size_t)N * 4);
  int* rowptr = (int*)alloc((size_t)(N + 1) * 4);
  int* cursor = (int*)alloc((size_t)N * 4);
  float* dinv = (float*)alloc((size_t)N * 4);
  int* bsum = (int*)alloc(4096);
  int* boff = (int*)alloc(4096);
  int* col = (int*)alloc((size_t)E * 4);
  float* wsrc = (float*)alloc((size_t)E * 4);

  // weight prep
  prep_w<<<(FDIM * HDIM + 255) / 256, 256, 0, stream>>>(W1, W2, W1t, W2t);

  // graph prep: degree -> dinv -> rowptr (scan) -> CSR fill
  hipMemsetAsync(deg, 0, (size_t)N * 4, stream);
  deg_k<<<(E + 255) / 256, 256, 0, stream>>>(dst, deg, E);
  dinv_k<<<(N + 255) / 256, 256, 0, stream>>>(deg, dinv, N);
  const int nb = (N + 1023) >> 10;
  scan_block<<<nb, 1024, 0, stream>>>(deg, rowptr, bsum, N);
  scan_sums<<<1, 64, 0, stream>>>(bsum, boff, nb);
  scan_add<<<nb, 1024, 0, stream>>>(rowptr, cursor, boff, N, E);
  fill_k<<<(E + 255) / 256, 256, 0, stream>>>(src, dst, dinv, cursor, col, wsrc, E);

  // MLP
  dim3 g1((N + 63) / 64, HDIM / 64);
  gemm_k<1, 1><<<g1, 256, 0, stream>>>((const void*)x, W1t, b1, (void*)h1, N, HDIM, FDIM);
  dim3 g2((N + 63) / 64, CDIM / 64);
  gemm_k<0, 0><<<g2, 256, 0, stream>>>((const void*)h1, W2t, b2, (void*)h0, N, CDIM, HDIM);

  // APPNP propagation (10 steps, ping-pong)
  const float* cur = h0;
  float* bufs[2] = {hA, hB};
  for (int t = 0; t < KSTEPS; ++t) {
    float* outb = bufs[t & 1];
    spmv_k<<<(N + 3) / 4, 256, 0, stream>>>(rowptr, col, wsrc, dinv, cur, h0, outb, N);
    cur = outb;
  }

  // log_softmax -> d_out (fp32)
  logsoftmax_k<<<(N + 3) / 4, 256, 0, stream>>>(cur, (float*)d_out, N);
}

// Round 2
// 1510.306 us; speedup vs baseline: 1.1780x; 1.1780x over previous
//
#include <hip/hip_runtime.h>
#include <hip/hip_bf16.h>

#define FDIM 512
#define HDIM 256
#define CDIM 64
#define KSTEPS 10

typedef __attribute__((ext_vector_type(8))) short bf16x8;
typedef __attribute__((ext_vector_type(4))) float f32x4;

static __device__ __forceinline__ unsigned short f2bf(float f) {
  union { float f; unsigned int u; } x; x.f = f;
  unsigned int u = x.u;
  return (unsigned short)((u + 0x7fffu + ((u >> 16) & 1u)) >> 16);  // RNE
}
static __device__ __forceinline__ float bfhi2f(unsigned int u_hi16_in_place) {
  union { unsigned int u; float f; } x; x.u = u_hi16_in_place; return x.f;
}

// ---------------- weight prep: fp32 [K][N] -> bf16 transposed [N][K] -------
__global__ void prep_w(const float* __restrict__ W1, const float* __restrict__ W2,
                       unsigned short* __restrict__ W1t, unsigned short* __restrict__ W2t) {
  int i = blockIdx.x * 256 + threadIdx.x;
  if (i < FDIM * HDIM) { int k = i / HDIM, n = i % HDIM; W1t[(size_t)n * FDIM + k] = f2bf(W1[i]); }
  if (i < HDIM * CDIM) { int k = i / CDIM, n = i % CDIM; W2t[(size_t)n * HDIM + k] = f2bf(W2[i]); }
}

// ---------------- graph prep -----------------------------------------------
__global__ void deg_k(const int* __restrict__ dst, int* __restrict__ deg, int E) {
  int i = blockIdx.x * 256 + threadIdx.x;
  if (i < E) atomicAdd(&deg[dst[i]], 1);
}

__global__ void dinv_k(const int* __restrict__ deg, float* __restrict__ dinv, int n) {
  int i = blockIdx.x * 256 + threadIdx.x;
  if (i < n) dinv[i] = rsqrtf((float)deg[i] + 1.0f);  // +1 self-loop
}

__global__ void scan_block(const int* __restrict__ deg, int* __restrict__ out,
                           int* __restrict__ bsum, int n) {
  __shared__ int tmp[1024];
  int i = blockIdx.x * 1024 + threadIdx.x;
  int v = (i < n) ? deg[i] : 0;
  tmp[threadIdx.x] = v;
  __syncthreads();
  for (int off = 1; off < 1024; off <<= 1) {
    int t = (threadIdx.x >= off) ? tmp[threadIdx.x - off] : 0;
    __syncthreads();
    tmp[threadIdx.x] += t;
    __syncthreads();
  }
  if (i < n) out[i] = tmp[threadIdx.x] - v;  // exclusive
  if (threadIdx.x == 1023) bsum[blockIdx.x] = tmp[1023];
}

__global__ void scan_sums(const int* __restrict__ bsum, int* __restrict__ boff, int nb) {
  if (threadIdx.x == 0 && blockIdx.x == 0) {
    int run = 0;
    for (int b = 0; b < nb; ++b) { boff[b] = run; run += bsum[b]; }
  }
}

__global__ void scan_add(int* __restrict__ rowptr, int* __restrict__ cursor,
                         const int* __restrict__ boff, int n, int total) {
  int i = blockIdx.x * 1024 + threadIdx.x;
  if (i < n) {
    int v = rowptr[i] + boff[blockIdx.x];
    rowptr[i] = v;
    cursor[i] = v;
  }
  if (i == 0) rowptr[n] = total;
}

// packed 8B record per edge: {src, bitcast(dinv[src])} -> one dirty line/edge
__global__ void fill_k(const int* __restrict__ src, const int* __restrict__ dst,
                       const float* __restrict__ dinv, int* __restrict__ cursor,
                       uint2* __restrict__ edges, int E) {
  int i = blockIdx.x * 256 + threadIdx.x;
  if (i < E) {
    int s = src[i], d = dst[i];
    int p = atomicAdd(&cursor[d], 1);
    union { float f; unsigned int u; } w; w.f = dinv[s];
    uint2 rec; rec.x = (unsigned int)s; rec.y = w.u;
    edges[p] = rec;
  }
}

// ---------------- bf16 MFMA GEMM: C[M,N] = act(A[M,K] @ Bt[N,K]^T + bias) ---
// MODE: 0 = fp32 out, 1 = relu -> bf16 out, 2 = fp32 out + bf16 dual out
template <int A_F32, int MODE>
__global__ __launch_bounds__(256) void gemm_k(const void* __restrict__ Ap,
                                              const unsigned short* __restrict__ Bt,
                                              const float* __restrict__ bias,
                                              void* __restrict__ Cp,
                                              unsigned short* __restrict__ Cp2,
                                              int M, int N, int K) {
  __shared__ unsigned short Al[64][40];  // +8 pad
  __shared__ unsigned short Bl[64][40];
  const int tid = threadIdx.x;
  const int wid = tid >> 6;
  const int lane = tid & 63;
  const int m0 = blockIdx.x * 64;
  const int n0 = blockIdx.y * 64;
  const int srow = tid >> 2;
  const int scg = (tid & 3) * 8;
  f32x4 acc[4] = {{0.f, 0.f, 0.f, 0.f}, {0.f, 0.f, 0.f, 0.f},
                  {0.f, 0.f, 0.f, 0.f}, {0.f, 0.f, 0.f, 0.f}};
  for (int k0 = 0; k0 < K; k0 += 32) {
    {
      const int gr = m0 + srow;
      unsigned short av[8];
      if (A_F32) {
        const float* A = (const float*)Ap;
        if (gr < M) {
          const float* p = A + (size_t)gr * K + k0 + scg;
#pragma unroll
          for (int j = 0; j < 8; ++j) av[j] = f2bf(p[j]);
        } else {
#pragma unroll
          for (int j = 0; j < 8; ++j) av[j] = 0;
        }
      } else {
        const unsigned short* A = (const unsigned short*)Ap;
        if (gr < M) {
          bf16x8 v = *(const bf16x8*)(A + (size_t)gr * K + k0 + scg);
          *(bf16x8*)av = v;
        } else {
#pragma unroll
          for (int j = 0; j < 8; ++j) av[j] = 0;
        }
      }
      *(bf16x8*)(&Al[srow][scg]) = *(bf16x8*)av;
    }
    {
      bf16x8 v = *(const bf16x8*)(Bt + (size_t)(n0 + srow) * K + k0 + scg);
      *(bf16x8*)(&Bl[srow][scg]) = v;
    }
    __syncthreads();
    bf16x8 a = *(const bf16x8*)(&Al[wid * 16 + (lane & 15)][(lane >> 4) * 8]);
#pragma unroll
    for (int nf = 0; nf < 4; ++nf) {
      bf16x8 b = *(const bf16x8*)(&Bl[nf * 16 + (lane & 15)][(lane >> 4) * 8]);
      acc[nf] = __builtin_amdgcn_mfma_f32_16x16x32_bf16(a, b, acc[nf], 0, 0, 0);
    }
    __syncthreads();
  }
#pragma unroll
  for (int nf = 0; nf < 4; ++nf) {
    const int colg = n0 + nf * 16 + (lane & 15);
    const float bb = bias[colg];
#pragma unroll
    for (int r = 0; r < 4; ++r) {
      const int rowg = m0 + wid * 16 + (lane >> 4) * 4 + r;
      if (rowg < M) {
        float v = acc[nf][r] + bb;
        if (MODE == 1) {
          v = fmaxf(v, 0.0f);
          ((unsigned short*)Cp)[(size_t)rowg * N + colg] = f2bf(v);
        } else {
          ((float*)Cp)[(size_t)rowg * N + colg] = v;
          if (MODE == 2) Cp2[(size_t)rowg * N + colg] = f2bf(v);
        }
      }
    }
  }
}

// ---------------- APPNP propagation step (bf16 state) ----------------------
// one wave per dst row. 16 lanes per edge-slot (4 bf16 ch = 8B each), 4 slots.
// agg = dinv[r]*(sum_e w_e * h[col_e]) + dinv[r]^2*h[r];  out = .9*agg+.1*h0
__global__ __launch_bounds__(256) void spmv_k(const int* __restrict__ rowptr,
                                              const uint2* __restrict__ edges,
                                              const float* __restrict__ dinv,
                                              const unsigned short* __restrict__ hin,
                                              const float* __restrict__ h0,
                                              unsigned short* __restrict__ hout, int n) {
  const int r = blockIdx.x * 4 + (threadIdx.x >> 6);
  if (r >= n) return;
  const int lane = threadIdx.x & 63;
  const int slot = lane >> 4;       // 0..3: which edge in the group of 4
  const int ch = (lane & 15) * 4;   // channel base (4 bf16 channels = 8B)
  const int e0 = rowptr[r], e1 = rowptr[r + 1];
  float a0 = 0.f, a1 = 0.f, a2 = 0.f, a3 = 0.f;
  for (int e = e0; e < e1; e += 4) {
    const int ee = e + slot;
    float w = 0.0f;
    unsigned int s = 0;
    if (ee < e1) {
      uint2 rec = edges[ee];
      s = rec.x;
      union { unsigned int u; float f; } x; x.u = rec.y; w = x.f;
    }
    uint2 hv = *(const uint2*)(hin + (size_t)s * 64 + ch);
    a0 += w * bfhi2f(hv.x << 16);
    a1 += w * bfhi2f(hv.x & 0xffff0000u);
    a2 += w * bfhi2f(hv.y << 16);
    a3 += w * bfhi2f(hv.y & 0xffff0000u);
  }
  // slot-reduce: xor 16 then 32 -> every lane has full sum; lanes 0-15 write
#pragma unroll
  for (int off = 16; off <= 32; off <<= 1) {
    a0 += __shfl_xor(a0, off, 64);
    a1 += __shfl_xor(a1, off, 64);
    a2 += __shfl_xor(a2, off, 64);
    a3 += __shfl_xor(a3, off, 64);
  }
  if (slot == 0) {
    const float di = dinv[r];
    const float dii = di * di;
    uint2 hs = *(const uint2*)(hin + (size_t)r * 64 + ch);
    const f32x4 h0v = *(const f32x4*)(h0 + (size_t)r * 64 + ch);
    float o0 = 0.9f * (di * a0 + dii * bfhi2f(hs.x << 16)) + 0.1f * h0v[0];
    float o1 = 0.9f * (di * a1 + dii * bfhi2f(hs.x & 0xffff0000u)) + 0.1f * h0v[1];
    float o2 = 0.9f * (di * a2 + dii * bfhi2f(hs.y << 16)) + 0.1f * h0v[2];
    float o3 = 0.9f * (di * a3 + dii * bfhi2f(hs.y & 0xffff0000u)) + 0.1f * h0v[3];
    uint2 pk;
    pk.x = ((unsigned int)f2bf(o1) << 16) | f2bf(o0);
    pk.y = ((unsigned int)f2bf(o3) << 16) | f2bf(o2);
    *(uint2*)(hout + (size_t)r * 64 + ch) = pk;
  }
}

// ---------------- log_softmax over 64 classes (bf16 in, fp32 out) ----------
__global__ __launch_bounds__(256) void logsoftmax_k(const unsigned short* __restrict__ h,
                                                    float* __restrict__ out, int n) {
  const int r = blockIdx.x * 4 + (threadIdx.x >> 6);
  if (r >= n) return;
  const int lane = threadIdx.x & 63;
  float v = bfhi2f(((unsigned int)h[(size_t)r * 64 + lane]) << 16);
  float m = v;
#pragma unroll
  for (int o = 32; o; o >>= 1) m = fmaxf(m, __shfl_xor(m, o, 64));
  float ex = expf(v - m);
  float s = ex;
#pragma unroll
  for (int o = 32; o; o >>= 1) s += __shfl_xor(s, o, 64);
  out[(size_t)r * 64 + lane] = v - m - logf(s);
}

extern "C" void kernel_launch(void* const* d_in, const int* in_sizes, int n_in,
                              void* d_out, int out_size, void* d_ws, size_t ws_size,
                              hipStream_t stream) {
  const float* x = (const float*)d_in[0];
  const float* W1 = (const float*)d_in[1];
  const float* b1 = (const float*)d_in[2];
  const float* W2 = (const float*)d_in[3];
  const float* b2 = (const float*)d_in[4];
  const int* ei = (const int*)d_in[5];
  const int E = in_sizes[5] / 2;
  const int N = in_sizes[0] / FDIM;
  const int* src = ei;
  const int* dst = ei + E;

  char* wp = (char*)d_ws;
  auto alloc = [&](size_t b) {
    char* p = wp;
    wp += (b + 255) & ~(size_t)255;
    return p;
  };
  unsigned short* W1t = (unsigned short*)alloc((size_t)HDIM * FDIM * 2);
  unsigned short* W2t = (unsigned short*)alloc((size_t)CDIM * HDIM * 2);
  unsigned short* h1 = (unsigned short*)alloc((size_t)N * HDIM * 2);
  float* h0 = (float*)alloc((size_t)N * CDIM * 4);
  unsigned short* hb0 = (unsigned short*)alloc((size_t)N * CDIM * 2);
  unsigned short* hA = (unsigned short*)alloc((size_t)N * CDIM * 2);
  unsigned short* hB = (unsigned short*)alloc((size_t)N * CDIM * 2);
  int* deg = (int*)alloc((size_t)N * 4);
  int* rowptr = (int*)alloc((size_t)(N + 1) * 4);
  int* cursor = (int*)alloc((size_t)N * 4);
  float* dinv = (float*)alloc((size_t)N * 4);
  int* bsum = (int*)alloc(4096);
  int* boff = (int*)alloc(4096);
  uint2* edges = (uint2*)alloc((size_t)E * 8);

  // weight prep
  prep_w<<<(FDIM * HDIM + 255) / 256, 256, 0, stream>>>(W1, W2, W1t, W2t);

  // graph prep: degree -> dinv -> rowptr (scan) -> CSR fill (packed records)
  hipMemsetAsync(deg, 0, (size_t)N * 4, stream);
  deg_k<<<(E + 255) / 256, 256, 0, stream>>>(dst, deg, E);
  dinv_k<<<(N + 255) / 256, 256, 0, stream>>>(deg, dinv, N);
  const int nb = (N + 1023) >> 10;
  scan_block<<<nb, 1024, 0, stream>>>(deg, rowptr, bsum, N);
  scan_sums<<<1, 64, 0, stream>>>(bsum, boff, nb);
  scan_add<<<nb, 1024, 0, stream>>>(rowptr, cursor, boff, N, E);
  fill_k<<<(E + 255) / 256, 256, 0, stream>>>(src, dst, dinv, cursor, edges, E);

  // MLP
  dim3 g1((N + 63) / 64, HDIM / 64);
  gemm_k<1, 1><<<g1, 256, 0, stream>>>((const void*)x, W1t, b1, (void*)h1, nullptr, N, HDIM, FDIM);
  dim3 g2((N + 63) / 64, CDIM / 64);
  gemm_k<0, 2><<<g2, 256, 0, stream>>>((const void*)h1, W2t, b2, (void*)h0, hb0, N, CDIM, HDIM);

  // APPNP propagation (10 steps, ping-pong, bf16 state)
  const unsigned short* cur = hb0;
  unsigned short* bufs[2] = {hA, hB};
  for (int t = 0; t < KSTEPS; ++t) {
    unsigned short* outb = bufs[t & 1];
    spmv_k<<<(N + 3) / 4, 256, 0, stream>>>(rowptr, edges, dinv, cur, h0, outb, N);
    cur = outb;
  }

  // log_softmax -> d_out (fp32)
  logsoftmax_k<<<(N + 3) / 4, 256, 0, stream>>>(cur, (float*)d_out, N);
}

// Round 3
// 1270.631 us; speedup vs baseline: 1.4003x; 1.1886x over previous
//
#include <hip/hip_runtime.h>
#include <hip/hip_bf16.h>

#define FDIM 512
#define HDIM 256
#define CDIM 64
#define KSTEPS 10

typedef __attribute__((ext_vector_type(8))) short bf16x8;
typedef __attribute__((ext_vector_type(4))) float f32x4;

static __device__ __forceinline__ unsigned short f2bf(float f) {
  union { float f; unsigned int u; } x; x.f = f;
  unsigned int u = x.u;
  return (unsigned short)((u + 0x7fffu + ((u >> 16) & 1u)) >> 16);  // RNE
}
static __device__ __forceinline__ float bfhi2f(unsigned int u) {
  union { unsigned int u; float f; } x; x.u = u; return x.f;
}

// ---------------- weight prep: fp32 [K][N] -> bf16 transposed [N][K] -------
__global__ void prep_w(const float* __restrict__ W1, const float* __restrict__ W2,
                       unsigned short* __restrict__ W1t, unsigned short* __restrict__ W2t) {
  int i = blockIdx.x * 256 + threadIdx.x;
  if (i < FDIM * HDIM) { int k = i / HDIM, n = i % HDIM; W1t[(size_t)n * FDIM + k] = f2bf(W1[i]); }
  if (i < HDIM * CDIM) { int k = i / CDIM, n = i % CDIM; W2t[(size_t)n * HDIM + k] = f2bf(W2[i]); }
}

// ---------------- graph prep -----------------------------------------------
__global__ void deg_k(const int* __restrict__ dst, int* __restrict__ deg, int E) {
  int i = blockIdx.x * 256 + threadIdx.x;
  if (i < E) atomicAdd(&deg[dst[i]], 1);
}

__global__ void dinv_k(const int* __restrict__ deg, float* __restrict__ dinv, int n) {
  int i = blockIdx.x * 256 + threadIdx.x;
  if (i < n) dinv[i] = rsqrtf((float)deg[i] + 1.0f);  // +1 self-loop
}

__global__ void scan_block(const int* __restrict__ deg, int* __restrict__ out,
                           int* __restrict__ bsum, int n) {
  __shared__ int tmp[1024];
  int i = blockIdx.x * 1024 + threadIdx.x;
  int v = (i < n) ? deg[i] : 0;
  tmp[threadIdx.x] = v;
  __syncthreads();
  for (int off = 1; off < 1024; off <<= 1) {
    int t = (threadIdx.x >= off) ? tmp[threadIdx.x - off] : 0;
    __syncthreads();
    tmp[threadIdx.x] += t;
    __syncthreads();
  }
  if (i < n) out[i] = tmp[threadIdx.x] - v;  // exclusive
  if (threadIdx.x == 1023) bsum[blockIdx.x] = tmp[1023];
}

__global__ void scan_sums(const int* __restrict__ bsum, int* __restrict__ boff, int nb) {
  if (threadIdx.x == 0 && blockIdx.x == 0) {
    int run = 0;
    for (int b = 0; b < nb; ++b) { boff[b] = run; run += bsum[b]; }
  }
}

__global__ void scan_add(int* __restrict__ rowptr, int* __restrict__ cursor,
                         const int* __restrict__ boff, int n, int total) {
  int i = blockIdx.x * 1024 + threadIdx.x;
  if (i < n) {
    int v = rowptr[i] + boff[blockIdx.x];
    rowptr[i] = v;
    cursor[i] = v;
  }
  if (i == 0) rowptr[n] = total;
}

// packed 8B record per edge: {src, bitcast(dinv[src])}
__global__ void fill_k(const int* __restrict__ src, const int* __restrict__ dst,
                       const float* __restrict__ dinv, int* __restrict__ cursor,
                       uint2* __restrict__ edges, int E) {
  int i = blockIdx.x * 256 + threadIdx.x;
  if (i < E) {
    int s = src[i], d = dst[i];
    int p = atomicAdd(&cursor[d], 1);
    union { float f; unsigned int u; } w; w.f = dinv[s];
    uint2 rec; rec.x = (unsigned int)s; rec.y = w.u;
    edges[p] = rec;
  }
}

// ---------------- GEMM1: h1 = relu(x @ W1 + b1), tile 64(M) x 256(N=all) ---
// A fp32 [M][512] read ONCE, converted inline. 4 waves, wave w: rows 16w..16w+15.
__global__ __launch_bounds__(256) void gemm1_k(const float* __restrict__ A,
                                               const unsigned short* __restrict__ Bt,
                                               const float* __restrict__ bias,
                                               unsigned short* __restrict__ C, int M) {
  __shared__ unsigned short Al[64][40];   // +8 pad
  __shared__ unsigned short Bl[256][40];  // 256 n-rows x 32 k
  const int tid = threadIdx.x;
  const int wid = tid >> 6;
  const int lane = tid & 63;
  const int m0 = blockIdx.x * 64;
  const int srow = tid >> 2;
  const int scg = (tid & 3) * 8;
  f32x4 acc[16];
#pragma unroll
  for (int i = 0; i < 16; ++i) acc[i] = (f32x4){0.f, 0.f, 0.f, 0.f};
  for (int k0 = 0; k0 < FDIM; k0 += 32) {
    // stage A 64x32 fp32->bf16
    {
      const int gr = m0 + srow;
      unsigned short av[8];
      if (gr < M) {
        const float* p = A + (size_t)gr * FDIM + k0 + scg;
#pragma unroll
        for (int j = 0; j < 8; ++j) av[j] = f2bf(p[j]);
      } else {
#pragma unroll
        for (int j = 0; j < 8; ++j) av[j] = 0;
      }
      *(bf16x8*)(&Al[srow][scg]) = *(bf16x8*)av;
    }
    // stage B 256x32 (4 rows per thread)
#pragma unroll
    for (int j = 0; j < 4; ++j) {
      const int br = srow + 64 * j;
      bf16x8 v = *(const bf16x8*)(Bt + (size_t)br * FDIM + k0 + scg);
      *(bf16x8*)(&Bl[br][scg]) = v;
    }
    __syncthreads();
    bf16x8 a = *(const bf16x8*)(&Al[wid * 16 + (lane & 15)][(lane >> 4) * 8]);
#pragma unroll
    for (int nf = 0; nf < 16; ++nf) {
      bf16x8 b = *(const bf16x8*)(&Bl[nf * 16 + (lane & 15)][(lane >> 4) * 8]);
      acc[nf] = __builtin_amdgcn_mfma_f32_16x16x32_bf16(a, b, acc[nf], 0, 0, 0);
    }
    __syncthreads();
  }
#pragma unroll
  for (int nf = 0; nf < 16; ++nf) {
    const int colg = nf * 16 + (lane & 15);
    const float bb = bias[colg];
#pragma unroll
    for (int r = 0; r < 4; ++r) {
      const int rowg = m0 + wid * 16 + (lane >> 4) * 4 + r;
      if (rowg < M) {
        float v = fmaxf(acc[nf][r] + bb, 0.0f);
        C[(size_t)rowg * HDIM + colg] = f2bf(v);
      }
    }
  }
}

// ---------------- GEMM2: h0 = h1 @ W2 + b2 -> bf16, tile 64x64 -------------
__global__ __launch_bounds__(256) void gemm2_k(const unsigned short* __restrict__ A,
                                               const unsigned short* __restrict__ Bt,
                                               const float* __restrict__ bias,
                                               unsigned short* __restrict__ C, int M) {
  __shared__ unsigned short Al[64][40];
  __shared__ unsigned short Bl[64][40];
  const int tid = threadIdx.x;
  const int wid = tid >> 6;
  const int lane = tid & 63;
  const int m0 = blockIdx.x * 64;
  const int srow = tid >> 2;
  const int scg = (tid & 3) * 8;
  f32x4 acc[4];
#pragma unroll
  for (int i = 0; i < 4; ++i) acc[i] = (f32x4){0.f, 0.f, 0.f, 0.f};
  for (int k0 = 0; k0 < HDIM; k0 += 32) {
    {
      const int gr = m0 + srow;
      if (gr < M) {
        bf16x8 v = *(const bf16x8*)(A + (size_t)gr * HDIM + k0 + scg);
        *(bf16x8*)(&Al[srow][scg]) = v;
      } else {
        bf16x8 z = {0, 0, 0, 0, 0, 0, 0, 0};
        *(bf16x8*)(&Al[srow][scg]) = z;
      }
    }
    {
      bf16x8 v = *(const bf16x8*)(Bt + (size_t)srow * HDIM + k0 + scg);
      *(bf16x8*)(&Bl[srow][scg]) = v;
    }
    __syncthreads();
    bf16x8 a = *(const bf16x8*)(&Al[wid * 16 + (lane & 15)][(lane >> 4) * 8]);
#pragma unroll
    for (int nf = 0; nf < 4; ++nf) {
      bf16x8 b = *(const bf16x8*)(&Bl[nf * 16 + (lane & 15)][(lane >> 4) * 8]);
      acc[nf] = __builtin_amdgcn_mfma_f32_16x16x32_bf16(a, b, acc[nf], 0, 0, 0);
    }
    __syncthreads();
  }
#pragma unroll
  for (int nf = 0; nf < 4; ++nf) {
    const int colg = nf * 16 + (lane & 15);
    const float bb = bias[colg];
#pragma unroll
    for (int r = 0; r < 4; ++r) {
      const int rowg = m0 + wid * 16 + (lane >> 4) * 4 + r;
      if (rowg < M) C[(size_t)rowg * CDIM + colg] = f2bf(acc[nf][r] + bb);
    }
  }
}

// ---------------- APPNP propagation step (bf16 state, 4-deep pipeline) -----
// one wave per dst row; 4 slots x 16 lanes; 16 edges per loop iteration.
__global__ __launch_bounds__(256) void spmv_k(const int* __restrict__ rowptr,
                                              const uint2* __restrict__ edges,
                                              const float* __restrict__ dinv,
                                              const unsigned short* __restrict__ hin,
                                              const unsigned short* __restrict__ h0,
                                              unsigned short* __restrict__ hout, int n) {
  const int r = blockIdx.x * 4 + (threadIdx.x >> 6);
  if (r >= n) return;
  const int lane = threadIdx.x & 63;
  const int slot = lane >> 4;
  const int ch = (lane & 15) * 4;
  const int e0 = rowptr[r], e1 = rowptr[r + 1];
  float a0 = 0.f, a1 = 0.f, a2 = 0.f, a3 = 0.f;
  for (int e = e0; e < e1; e += 16) {
    uint2 rec[4];
#pragma unroll
    for (int j = 0; j < 4; ++j) {
      const int ee = e + slot + 4 * j;
      uint2 rc; rc.x = 0u; rc.y = 0u;   // w=0 for inactive
      if (ee < e1) rc = edges[ee];
      rec[j] = rc;
    }
    uint2 hv[4];
#pragma unroll
    for (int j = 0; j < 4; ++j)
      hv[j] = *(const uint2*)(hin + (size_t)rec[j].x * 64 + ch);
#pragma unroll
    for (int j = 0; j < 4; ++j) {
      union { unsigned int u; float f; } w; w.u = rec[j].y;
      a0 += w.f * bfhi2f(hv[j].x << 16);
      a1 += w.f * bfhi2f(hv[j].x & 0xffff0000u);
      a2 += w.f * bfhi2f(hv[j].y << 16);
      a3 += w.f * bfhi2f(hv[j].y & 0xffff0000u);
    }
  }
#pragma unroll
  for (int off = 16; off <= 32; off <<= 1) {
    a0 += __shfl_xor(a0, off, 64);
    a1 += __shfl_xor(a1, off, 64);
    a2 += __shfl_xor(a2, off, 64);
    a3 += __shfl_xor(a3, off, 64);
  }
  if (slot == 0) {
    const float di = dinv[r];
    const float dii = di * di;
    uint2 hs = *(const uint2*)(hin + (size_t)r * 64 + ch);
    uint2 hz = *(const uint2*)(h0 + (size_t)r * 64 + ch);
    float o0 = 0.9f * (di * a0 + dii * bfhi2f(hs.x << 16)) + 0.1f * bfhi2f(hz.x << 16);
    float o1 = 0.9f * (di * a1 + dii * bfhi2f(hs.x & 0xffff0000u)) + 0.1f * bfhi2f(hz.x & 0xffff0000u);
    float o2 = 0.9f * (di * a2 + dii * bfhi2f(hs.y << 16)) + 0.1f * bfhi2f(hz.y << 16);
    float o3 = 0.9f * (di * a3 + dii * bfhi2f(hs.y & 0xffff0000u)) + 0.1f * bfhi2f(hz.y & 0xffff0000u);
    uint2 pk;
    pk.x = ((unsigned int)f2bf(o1) << 16) | f2bf(o0);
    pk.y = ((unsigned int)f2bf(o3) << 16) | f2bf(o2);
    *(uint2*)(hout + (size_t)r * 64 + ch) = pk;
  }
}

// ---------------- log_softmax over 64 classes (bf16 in, fp32 out) ----------
__global__ __launch_bounds__(256) void logsoftmax_k(const unsigned short* __restrict__ h,
                                                    float* __restrict__ out, int n) {
  const int r = blockIdx.x * 4 + (threadIdx.x >> 6);
  if (r >= n) return;
  const int lane = threadIdx.x & 63;
  float v = bfhi2f(((unsigned int)h[(size_t)r * 64 + lane]) << 16);
  float m = v;
#pragma unroll
  for (int o = 32; o; o >>= 1) m = fmaxf(m, __shfl_xor(m, o, 64));
  float ex = expf(v - m);
  float s = ex;
#pragma unroll
  for (int o = 32; o; o >>= 1) s += __shfl_xor(s, o, 64);
  out[(size_t)r * 64 + lane] = v - m - logf(s);
}

extern "C" void kernel_launch(void* const* d_in, const int* in_sizes, int n_in,
                              void* d_out, int out_size, void* d_ws, size_t ws_size,
                              hipStream_t stream) {
  const float* x = (const float*)d_in[0];
  const float* W1 = (const float*)d_in[1];
  const float* b1 = (const float*)d_in[2];
  const float* W2 = (const float*)d_in[3];
  const float* b2 = (const float*)d_in[4];
  const int* ei = (const int*)d_in[5];
  const int E = in_sizes[5] / 2;
  const int N = in_sizes[0] / FDIM;
  const int* src = ei;
  const int* dst = ei + E;

  char* wp = (char*)d_ws;
  auto alloc = [&](size_t b) {
    char* p = wp;
    wp += (b + 255) & ~(size_t)255;
    return p;
  };
  unsigned short* W1t = (unsigned short*)alloc((size_t)HDIM * FDIM * 2);
  unsigned short* W2t = (unsigned short*)alloc((size_t)CDIM * HDIM * 2);
  unsigned short* h1 = (unsigned short*)alloc((size_t)N * HDIM * 2);
  unsigned short* hb0 = (unsigned short*)alloc((size_t)N * CDIM * 2);
  unsigned short* hA = (unsigned short*)alloc((size_t)N * CDIM * 2);
  unsigned short* hB = (unsigned short*)alloc((size_t)N * CDIM * 2);
  int* deg = (int*)alloc((size_t)N * 4);
  int* rowptr = (int*)alloc((size_t)(N + 1) * 4);
  int* cursor = (int*)alloc((size_t)N * 4);
  float* dinv = (float*)alloc((size_t)N * 4);
  int* bsum = (int*)alloc(4096);
  int* boff = (int*)alloc(4096);
  uint2* edges = (uint2*)alloc((size_t)E * 8);

  // weight prep
  prep_w<<<(FDIM * HDIM + 255) / 256, 256, 0, stream>>>(W1, W2, W1t, W2t);

  // graph prep
  hipMemsetAsync(deg, 0, (size_t)N * 4, stream);
  deg_k<<<(E + 255) / 256, 256, 0, stream>>>(dst, deg, E);
  dinv_k<<<(N + 255) / 256, 256, 0, stream>>>(deg, dinv, N);
  const int nb = (N + 1023) >> 10;
  scan_block<<<nb, 1024, 0, stream>>>(deg, rowptr, bsum, N);
  scan_sums<<<1, 64, 0, stream>>>(bsum, boff, nb);
  scan_add<<<nb, 1024, 0, stream>>>(rowptr, cursor, boff, N, E);
  fill_k<<<(E + 255) / 256, 256, 0, stream>>>(src, dst, dinv, cursor, edges, E);

  // MLP
  gemm1_k<<<(N + 63) / 64, 256, 0, stream>>>(x, W1t, b1, h1, N);
  gemm2_k<<<(N + 63) / 64, 256, 0, stream>>>(h1, W2t, b2, hb0, N);

  // APPNP propagation (10 steps, ping-pong, bf16 state, bf16 teleport)
  const unsigned short* cur = hb0;
  unsigned short* bufs[2] = {hA, hB};
  for (int t = 0; t < KSTEPS; ++t) {
    unsigned short* outb = bufs[t & 1];
    spmv_k<<<(N + 3) / 4, 256, 0, stream>>>(rowptr, edges, dinv, cur, hb0, outb, N);
    cur = outb;
  }

  // log_softmax -> d_out (fp32)
  logsoftmax_k<<<(N + 3) / 4, 256, 0, stream>>>(cur, (float*)d_out, N);
}